// Round 2
// baseline (2258.326 us; speedup 1.0000x reference)
//
#include <hip/hip_runtime.h>
#include <math.h>

#define BATCH 64
#define SEQL 128
#define UNITS 128
#define G4 512

typedef _Float16 h2 __attribute__((ext_vector_type(2)));
typedef _Float16 h4 __attribute__((ext_vector_type(4)));
typedef _Float16 h8 __attribute__((ext_vector_type(8)));
typedef __fp16 pk2 __attribute__((ext_vector_type(2)));   // cvt_pkrtz native type
typedef float f4 __attribute__((ext_vector_type(4)));

__device__ __forceinline__ h2 mkh2(_Float16 a, _Float16 b) { h2 r; r[0] = a; r[1] = b; return r; }

__device__ __forceinline__ float fdot2f(h2 a, h2 b, float c) {
#if __has_builtin(__builtin_amdgcn_fdot2)
  return __builtin_amdgcn_fdot2(a, b, c, false);
#else
  return c + (float)a[0] * (float)b[0] + (float)a[1] * (float)b[1];
#endif
}

__device__ __forceinline__ float sigm(float x) { return 1.0f / (1.0f + __expf(-x)); }

__device__ __forceinline__ h8 pack8(f4 a, f4 b) {
  union { h8 v; pk2 p[4]; } u;
  u.p[0] = __builtin_amdgcn_cvt_pkrtz(a[0], a[1]);
  u.p[1] = __builtin_amdgcn_cvt_pkrtz(a[2], a[3]);
  u.p[2] = __builtin_amdgcn_cvt_pkrtz(b[0], b[1]);
  u.p[3] = __builtin_amdgcn_cvt_pkrtz(b[2], b[3]);
  return u.v;
}

// K0: convert weights to f16. Recurrent weights -> paired layout R2[k2][col] =
// (w[2k2][col], w[2k2+1][col]) for v_dot2. enc_kernel -> transposed EkT[col][k]
// (half, k-contiguous) = MFMA B-operand layout for K1.
__global__ __launch_bounds__(256) void k0_prep(
    const float* __restrict__ rke, const float* __restrict__ rkd,
    const float* __restrict__ k2e, const float* __restrict__ k2d,
    const float* __restrict__ ek,
    h2* __restrict__ R2e, h2* __restrict__ R2d,
    h2* __restrict__ K22e, h2* __restrict__ K22d,
    _Float16* __restrict__ EkT)
{
  int blk = blockIdx.x, tid = threadIdx.x;
  if (blk < 256) {
    const float* src = (blk < 128) ? rke : rkd;
    h2* dst = (blk < 128) ? R2e : R2d;
    int idx = (blk & 127) * 256 + tid;       // [0, 32768)
    int k2 = idx >> 9, col = idx & 511;
    dst[idx] = mkh2((_Float16)src[(2 * k2) * G4 + col], (_Float16)src[(2 * k2 + 1) * G4 + col]);
  } else if (blk < 320) {
    const float* src = (blk < 288) ? k2e : k2d;
    h2* dst = (blk < 288) ? K22e : K22d;
    int idx = ((blk - 256) & 31) * 256 + tid; // [0, 8192)
    int k2 = idx >> 7, col = idx & 127;
    dst[idx] = mkh2((_Float16)src[(2 * k2) * UNITS + col], (_Float16)src[(2 * k2 + 1) * UNITS + col]);
  } else {
    int idx = (blk - 320) * 256 + tid;        // [0, 8192), 8 outputs each
    int col = idx >> 4;
    int k0 = (idx & 15) * 8;
#pragma unroll
    for (int i = 0; i < 8; ++i)
      EkT[col * 128 + k0 + i] = (_Float16)ek[(k0 + i) * G4 + col];
  }
}

// K1: xgates_enc[r=(b,t)][col] = X1[r,:] @ enc_kernel + enc_bias, via MFMA f16.
// A = X rows (f32 -> pkrtz in-register), B = EkT (k-contiguous per col).
__global__ __launch_bounds__(256) void k1_xgates(
    const float* __restrict__ X, const _Float16* __restrict__ EkT,
    const float* __restrict__ bias, _Float16* __restrict__ xg)
{
  int l = threadIdx.x & 63;
  int w = threadIdx.x >> 6;
  int rt = blockIdx.x * 64 + w * 16;
  int m0 = l & 15, kg = l >> 4;
  int row = rt + m0;                 // A-operand row for this lane
  int bb = row >> 7, tt = row & 127;
  const float* xrow = X + (size_t)bb * (2 * SEQL * 128) + tt * 128;  // X[b,0,t,:]
  f4 acc[32];
  for (int nt = 0; nt < 32; ++nt)
    for (int qq = 0; qq < 4; ++qq) acc[nt][qq] = 0.f;
  for (int kt = 0; kt < 4; ++kt) {
    int k0 = kt * 32 + kg * 8;
    f4 a0 = *(const f4*)(xrow + k0);
    f4 a1 = *(const f4*)(xrow + k0 + 4);
    h8 af = pack8(a0, a1);
#pragma unroll
    for (int nt = 0; nt < 32; ++nt) {
      int col = nt * 16 + m0;
      h8 bf = *(const h8*)(EkT + col * 128 + k0);
      acc[nt] = __builtin_amdgcn_mfma_f32_16x16x32_f16(af, bf, acc[nt], 0, 0, 0);
    }
  }
#pragma unroll
  for (int nt = 0; nt < 32; ++nt) {
    int col = nt * 16 + m0;
    float bc = bias[col];
#pragma unroll
    for (int r = 0; r < 4; ++r) {
      int rowo = rt + kg * 4 + r;   // C layout: row=(lane>>4)*4+reg, col=lane&15
      xg[(size_t)rowo * G4 + col] = (_Float16)(acc[nt][r] + bc);
    }
  }
}

// K2/K3: skip-LSTM recurrence, one block per batch, 320 threads (5 waves).
// Waves 0-3: the 512 gate columns (2 each via paired f16 dot2); wave 4: the 128
// skip columns. State [i,f,c,o] as f16 (dbuf), cell f32, h-history 17-ring.
__global__ __launch_bounds__(320) void lstm_seq(
    const _Float16* __restrict__ xg,   // enc: [8192][512] f16; dec: null
    const float* __restrict__ re_in,   // dec: RE[64][128]
    const float* __restrict__ Wx,      // dec: dec_kernel [128][512]
    const float* __restrict__ bx,      // dec: dec_bias [512]
    const h2* __restrict__ R2,         // [64][512] paired rkernel
    const h2* __restrict__ K22,        // [64][128] paired kernel2
    const float* __restrict__ bias2,   // [128]
    const float* __restrict__ s0p,
    float* __restrict__ re_out,        // enc: RE out
    _Float16* __restrict__ flat,       // dec: flat16 [64][16384]
    int is_dec)
{
  __shared__ _Float16 st[2][G4];       // [i,f,c,o] state, double-buffered
  __shared__ float cst[2][UNITS];      // cell state f32
  __shared__ _Float16 hist[17][UNITS]; // h ring (skip lag = 16)
  __shared__ float tc_s[UNITS];        // tanh(xc + hc@Rc) stage
  __shared__ float hs_s[UNITS];        // sigmoid(skip) stage
  __shared__ float xdec[G4];           // decoder constant x-gates
  __shared__ float xrow[UNITS];

  const int tid = threadIdx.x;
  const int b = blockIdx.x;
  const float s0 = s0p[0];

  for (int i = tid; i < G4; i += 320) st[0][i] = (_Float16)0.f;
  for (int i = tid; i < UNITS; i += 320) cst[0][i] = 0.f;
  for (int i = tid; i < 17 * UNITS; i += 320) (&hist[0][0])[i] = (_Float16)0.f;
  if (is_dec) for (int i = tid; i < UNITS; i += 320) xrow[i] = re_in[b * UNITS + i];
  __syncthreads();

  if (is_dec && tid < 256) {           // decoder: x@kernel+bias once (P is constant)
    int c0 = 2 * tid;
    float a0 = bx[c0], a1 = bx[c0 + 1];
    for (int k = 0; k < UNITS; ++k) {
      float xv = xrow[k];
      a0 = fmaf(xv, Wx[k * G4 + c0], a0);
      a1 = fmaf(xv, Wx[k * G4 + c0 + 1], a1);
    }
    xdec[c0] = a0; xdec[c0 + 1] = a1;
  }
  __syncthreads();

  for (int t = 0; t < SEQL; ++t) {
    const int p = t & 1, q = p ^ 1;
    if (tid < 256) {
      const int c0 = 2 * tid;
      const int g = tid >> 6;          // wave-uniform gate id
      float a0, a1;
      if (is_dec) { a0 = xdec[c0]; a1 = xdec[c0 + 1]; }
      else {
        const _Float16* xp = xg + (size_t)(b * SEQL + t) * G4 + c0;
        a0 = (float)xp[0]; a1 = (float)xp[1];
      }
      const h2* stv = (const h2*)&st[p][g * 128];  // LDS broadcast reads
      const h2* wp = R2 + c0;
      float b0 = 0.f, b1 = 0.f;
#pragma unroll 16
      for (int k2 = 0; k2 < 64; k2 += 2) {
        h2 h0 = stv[k2];
        h2 h1 = stv[k2 + 1];
        h4 w0 = *(const h4*)(wp + (size_t)k2 * G4);
        h4 w1 = *(const h4*)(wp + (size_t)(k2 + 1) * G4);
        a0 = fdot2f(h0, mkh2(w0[0], w0[1]), a0);
        a1 = fdot2f(h0, mkh2(w0[2], w0[3]), a1);
        b0 = fdot2f(h1, mkh2(w1[0], w1[1]), b0);
        b1 = fdot2f(h1, mkh2(w1[2], w1[3]), b1);
      }
      a0 += b0; a1 += b1;
      if (g == 2) {                    // c-gate: stage tanh; cell written phase 2
        tc_s[c0 - 256] = tanhf(a0);
        tc_s[c0 - 255] = tanhf(a1);
      } else {
        st[q][c0] = (_Float16)sigm(a0);
        st[q][c0 + 1] = (_Float16)sigm(a1);
      }
    } else {                           // skip path: sigmoid(h_{t-16} @ kernel2 + b2)
      const int sc0 = 2 * (tid - 256);
      const int rs = (t + 1) % 17;     // slot of h_{t-16} (zeros for t<16)
      const h2* hv = (const h2*)&hist[rs][0];
      const h2* wp = K22 + sc0;
      float a0 = bias2[sc0], a1 = bias2[sc0 + 1];
      float b0 = 0.f, b1 = 0.f;
#pragma unroll 16
      for (int k2 = 0; k2 < 64; k2 += 2) {
        h2 h0 = hv[k2], h1 = hv[k2 + 1];
        h4 w0 = *(const h4*)(wp + (size_t)k2 * UNITS);
        h4 w1 = *(const h4*)(wp + (size_t)(k2 + 1) * UNITS);
        a0 = fdot2f(h0, mkh2(w0[0], w0[1]), a0);
        a1 = fdot2f(h0, mkh2(w0[2], w0[3]), a1);
        b0 = fdot2f(h1, mkh2(w1[0], w1[1]), b0);
        b1 = fdot2f(h1, mkh2(w1[2], w1[3]), b1);
      }
      a0 += b0; a1 += b1;
      hs_s[sc0] = sigm(a0);
      hs_s[sc0 + 1] = sigm(a1);
    }
    __syncthreads();
    if (tid < UNITS) {                 // phase 2: cell + output
      const int j = tid;
      float iv = (float)st[q][j];
      float fv = (float)st[q][128 + j];
      float cn = fv * cst[p][j] + iv * tc_s[j];
      cst[q][j] = cn;
      st[q][256 + j] = (_Float16)cn;   // hc for next step = new cell
      float ov = (float)st[q][384 + j];
      float hc = ov * tanhf(cn);
      float h = s0 * hc + (1.0f - s0) * hs_s[j];
      hist[t % 17][j] = (_Float16)h;
      if (is_dec) flat[(size_t)b * 16384 + t * 128 + j] = (_Float16)h;
      else if (t == SEQL - 1) re_out[b * UNITS + j] = h;
    }
    __syncthreads();
  }
}

// K4: Y[b][j] = flat[b,:] @ W[j,:] + bias[j]. W streamed f32 from HBM (1 GiB),
// converted to f16 in-register (amortized over 64 batches), MFMA 16x16x32.
// 512 blocks x 256 thr; waves split (jsub x khalf), k-halves reduced via LDS.
__global__ __launch_bounds__(256) void k4_dense(
    const float* __restrict__ W, const _Float16* __restrict__ flat,
    const float* __restrict__ bias, float* __restrict__ out)
{
  __shared__ f4 red[2][4][64];
  const int tid = threadIdx.x;
  const int l = tid & 63, w = tid >> 6;
  const int jsub = w & 1, khalf = w >> 1;
  const int j0 = blockIdx.x * 32 + jsub * 16;
  const int m0 = l & 15, kg = l >> 4;
  const size_t jrow = j0 + m0;
  const float* wrow = W + jrow * 16384;
  f4 acc[4];
  for (int bt = 0; bt < 4; ++bt)
    for (int qq = 0; qq < 4; ++qq) acc[bt][qq] = 0.f;
  const int ktbeg = khalf * 256;
  for (int kt = ktbeg; kt < ktbeg + 256; ++kt) {
    const int k0 = kt * 32 + kg * 8;
    f4 a0 = *(const f4*)(wrow + k0);
    f4 a1 = *(const f4*)(wrow + k0 + 4);
    h8 af = pack8(a0, a1);
#pragma unroll
    for (int bt = 0; bt < 4; ++bt) {
      const int col = bt * 16 + m0;    // batch column
      h8 bf = *(const h8*)(flat + (size_t)col * 16384 + k0);
      acc[bt] = __builtin_amdgcn_mfma_f32_16x16x32_f16(af, bf, acc[bt], 0, 0, 0);
    }
  }
  if (khalf == 1) {
#pragma unroll
    for (int bt = 0; bt < 4; ++bt) red[jsub][bt][l] = acc[bt];
  }
  __syncthreads();
  if (khalf == 0) {
#pragma unroll
    for (int bt = 0; bt < 4; ++bt) {
      f4 o = acc[bt];
      f4 r = red[jsub][bt][l];
      const int bcol = bt * 16 + m0;
#pragma unroll
      for (int rg = 0; rg < 4; ++rg) {
        const int j = j0 + kg * 4 + rg;
        out[(size_t)bcol * 16384 + j] = o[rg] + r[rg] + bias[j];
      }
    }
  }
}

extern "C" void kernel_launch(void* const* d_in, const int* in_sizes, int n_in,
                              void* d_out, int out_size, void* d_ws, size_t ws_size,
                              hipStream_t stream) {
  const float* X      = (const float*)d_in[0];
  const float* ek     = (const float*)d_in[1];
  const float* erk    = (const float*)d_in[2];
  const float* ek2    = (const float*)d_in[3];
  const float* ebias  = (const float*)d_in[4];
  const float* ebias2 = (const float*)d_in[5];
  const float* es0    = (const float*)d_in[6];
  const float* dk     = (const float*)d_in[7];
  const float* drk    = (const float*)d_in[8];
  const float* dk2    = (const float*)d_in[9];
  const float* dbias  = (const float*)d_in[10];
  const float* dbias2 = (const float*)d_in[11];
  const float* ds0    = (const float*)d_in[12];
  const float* dw     = (const float*)d_in[13];
  const float* db     = (const float*)d_in[14];
  float* out = (float*)d_out;
  (void)in_sizes; (void)n_in; (void)out_size; (void)ws_size;

  char* ws = (char*)d_ws;
  size_t off = 0;
  auto carve = [&](size_t bytes) -> void* {
    void* p = (void*)(ws + off);
    off += (bytes + 255) & ~(size_t)255;
    return p;
  };
  h2* R2e        = (h2*)carve((size_t)64 * 512 * sizeof(h2));
  h2* R2d        = (h2*)carve((size_t)64 * 512 * sizeof(h2));
  h2* K22e       = (h2*)carve((size_t)64 * 128 * sizeof(h2));
  h2* K22d       = (h2*)carve((size_t)64 * 128 * sizeof(h2));
  _Float16* EkT  = (_Float16*)carve((size_t)512 * 128 * sizeof(_Float16));
  _Float16* xgv  = (_Float16*)carve((size_t)8192 * 512 * sizeof(_Float16));
  _Float16* flat = (_Float16*)carve((size_t)64 * 16384 * sizeof(_Float16));
  float* RE      = (float*)carve((size_t)64 * 128 * sizeof(float));

  k0_prep<<<dim3(352), dim3(256), 0, stream>>>(erk, drk, ek2, dk2, ek,
                                               R2e, R2d, K22e, K22d, EkT);
  k1_xgates<<<dim3(128), dim3(256), 0, stream>>>(X, EkT, ebias, xgv);
  lstm_seq<<<dim3(64), dim3(320), 0, stream>>>(
      xgv, (const float*)nullptr, (const float*)nullptr, (const float*)nullptr,
      R2e, K22e, ebias2, es0, RE, (_Float16*)nullptr, 0);
  lstm_seq<<<dim3(64), dim3(320), 0, stream>>>(
      (const _Float16*)nullptr, RE, dk, dbias,
      R2d, K22d, dbias2, ds0, (float*)nullptr, flat, 1);
  k4_dense<<<dim3(512), dim3(256), 0, stream>>>(dw, flat, db, out);
}